// Round 1
// baseline (5965.669 us; speedup 1.0000x reference)
//
#include <hip/hip_runtime.h>
#include <math.h>

// ---------------- degree histogram ----------------
__global__ __launch_bounds__(256) void k_deg(const int* __restrict__ dst,
                                             float* __restrict__ deg, int E) {
    int i = blockIdx.x * 256 + threadIdx.x;
    if (i < E) atomicAdd(&deg[dst[i]], 1.0f);
}

__global__ __launch_bounds__(256) void k_invdeg(float* deg, int n) {
    int i = blockIdx.x * 256 + threadIdx.x;
    if (i < n) {
        float d = deg[i];
        deg[i] = d > 0.0f ? 1.0f / d : 0.0f;
    }
}

// ------- scatter-add: agg[dst] += h[src]  (segment_sum) -------
// one thread per (edge, float4 chunk): E*16 threads, 4 f32 atomics each
__global__ __launch_bounds__(256) void k_scatter(const float* __restrict__ h,
                                                 const int* __restrict__ src,
                                                 const int* __restrict__ dst,
                                                 float* __restrict__ agg, int E) {
    int gid = blockIdx.x * 256 + threadIdx.x;
    int e = gid >> 4;
    if (e >= E) return;
    int c = (gid & 15) * 4;
    int s = src[e], d = dst[e];
    float4 v = *(const float4*)&h[(size_t)s * 64 + c];
    float* a = &agg[(size_t)d * 64 + c];
    atomicAdd(a + 0, v.x);
    atomicAdd(a + 1, v.y);
    atomicAdd(a + 2, v.z);
    atomicAdd(a + 3, v.w);
}

// ---- fused node matmul: out[N,64] = act([A0(xscale)|A1] @ [W0;W1] + bias) ----
// 64 rows per block, 256 threads = 16 colgroups x 16 rowgroups, 4x4 reg tile.
// sA chunk-XOR swizzle: row stride K*4B is bank-aligned -> 4-way conflict
// without swizzle; with c' = c ^ (row>>2 & 3) reads are <=2-way (free, m136).
template <int K0, int K1, bool RELU>
__global__ __launch_bounds__(256) void node_mm(
    const float* __restrict__ A0, const float* __restrict__ scale0,
    const float* __restrict__ A1, const float* __restrict__ W0,
    const float* __restrict__ W1, const float* __restrict__ bias,
    float* __restrict__ out, int n) {
    constexpr int K = K0 + K1;
    constexpr int KV = K / 4;
    __shared__ float sA[64 * K];   // K=128 -> 32 KB
    __shared__ float sW[K * 64];   // K=128 -> 32 KB  (total exactly 64 KB)
    const int tid = threadIdx.x;
    const int row0 = blockIdx.x * 64;

    // stage W
    for (int i = tid; i < K0 * 16; i += 256)
        ((float4*)sW)[i] = ((const float4*)W0)[i];
    if (K1 > 0) {
        for (int i = tid; i < K1 * 16; i += 256)
            ((float4*)sW)[K0 * 16 + i] = ((const float4*)W1)[i];
    }

    // stage A tile (swizzled placement)
    for (int idx = tid; idx < 64 * KV; idx += 256) {
        int r = idx / KV, kc = idx % KV;
        int k = kc * 4;
        int grow = row0 + r;
        float4 v = make_float4(0.f, 0.f, 0.f, 0.f);
        if (grow < n) {
            if (k < K0) {
                v = *(const float4*)&A0[(size_t)grow * K0 + k];
                if (scale0) {
                    float sc = scale0[grow];
                    v.x *= sc; v.y *= sc; v.z *= sc; v.w *= sc;
                }
            } else {
                v = *(const float4*)&A1[(size_t)grow * K1 + (k - K0)];
            }
        }
        int kcs = kc ^ ((r >> 2) & 3);
        *(float4*)&sA[r * K + kcs * 4] = v;
    }
    __syncthreads();

    const int tc = tid & 15;   // cols 4*tc..4*tc+3
    const int tr = tid >> 4;   // rows 4*tr..4*tr+3
    const int sw = tr & 3;
    float4 acc[4];
#pragma unroll
    for (int rr = 0; rr < 4; ++rr) acc[rr] = make_float4(0.f, 0.f, 0.f, 0.f);

#pragma unroll 4
    for (int kc = 0; kc < KV; ++kc) {
        int ks = (kc ^ sw) * 4;
        float4 a[4], w[4];
#pragma unroll
        for (int rr = 0; rr < 4; ++rr)
            a[rr] = *(const float4*)&sA[(tr * 4 + rr) * K + ks];
#pragma unroll
        for (int kk = 0; kk < 4; ++kk)
            w[kk] = *(const float4*)&sW[(kc * 4 + kk) * 64 + tc * 4];
#pragma unroll
        for (int kk = 0; kk < 4; ++kk) {
#pragma unroll
            for (int rr = 0; rr < 4; ++rr) {
                float av = (&a[rr].x)[kk];
                acc[rr].x = fmaf(av, w[kk].x, acc[rr].x);
                acc[rr].y = fmaf(av, w[kk].y, acc[rr].y);
                acc[rr].z = fmaf(av, w[kk].z, acc[rr].z);
                acc[rr].w = fmaf(av, w[kk].w, acc[rr].w);
            }
        }
    }

    float4 b4 = make_float4(0.f, 0.f, 0.f, 0.f);
    if (bias) b4 = *(const float4*)&bias[tc * 4];
#pragma unroll
    for (int rr = 0; rr < 4; ++rr) {
        int r = row0 + tr * 4 + rr;
        if (r < n) {
            float4 v = acc[rr];
            v.x += b4.x; v.y += b4.y; v.z += b4.z; v.w += b4.w;
            if (RELU) {
                v.x = fmaxf(v.x, 0.f); v.y = fmaxf(v.y, 0.f);
                v.z = fmaxf(v.z, 0.f); v.w = fmaxf(v.w, 0.f);
            }
            *(float4*)&out[(size_t)r * 64 + tc * 4] = v;
        }
    }
}

// ---- edge scorer: out[e] = tanh( relu(P[s]+Q[d]) . w2 + b2 ) ----
// 16 lanes per edge, float4 per lane, shfl_xor(width 16) reduce
__global__ __launch_bounds__(256) void k_score(
    const float* __restrict__ P, const float* __restrict__ Q,
    const int* __restrict__ msrc, const int* __restrict__ mdst,
    const float* __restrict__ w2, const float* __restrict__ b2,
    float* __restrict__ out, int M) {
    int gid = blockIdx.x * 256 + threadIdx.x;
    int e = gid >> 4;
    if (e >= M) return;
    int l = gid & 15;
    int s = msrc[e], d = mdst[e];
    float4 p = *(const float4*)&P[(size_t)s * 64 + l * 4];
    float4 q = *(const float4*)&Q[(size_t)d * 64 + l * 4];
    float4 w = *(const float4*)&w2[l * 4];
    float ux = fmaxf(p.x + q.x, 0.f);
    float uy = fmaxf(p.y + q.y, 0.f);
    float uz = fmaxf(p.z + q.z, 0.f);
    float uw = fmaxf(p.w + q.w, 0.f);
    float partial = ux * w.x + uy * w.y + uz * w.z + uw * w.w;
#pragma unroll
    for (int m = 1; m < 16; m <<= 1) partial += __shfl_xor(partial, m, 16);
    if (l == 0) out[e] = tanhf(partial + b2[0]);
}

extern "C" void kernel_launch(void* const* d_in, const int* in_sizes, int n_in,
                              void* d_out, int out_size, void* d_ws, size_t ws_size,
                              hipStream_t stream) {
    const float* x      = (const float*)d_in[0];
    const int*   ei     = (const int*)d_in[1];
    const int*   mei    = (const int*)d_in[2];
    const float* lin1_w = (const float*)d_in[3];
    const float* lin1_b = (const float*)d_in[4];
    const float* lin2_w = (const float*)d_in[5];
    const float* lin2_b = (const float*)d_in[6];
    const float* c1_wl  = (const float*)d_in[7];
    const float* c1_bl  = (const float*)d_in[8];
    const float* c1_wr  = (const float*)d_in[9];
    const float* c2_wl  = (const float*)d_in[10];
    const float* c2_bl  = (const float*)d_in[11];
    const float* c2_wr  = (const float*)d_in[12];
    const float* mlp_w1 = (const float*)d_in[13];
    const float* mlp_b1 = (const float*)d_in[14];
    const float* mlp_w2 = (const float*)d_in[15];
    const float* mlp_b2 = (const float*)d_in[16];

    const int N = in_sizes[0] / 128;
    const int E = in_sizes[1] / 2;
    const int M = in_sizes[2] / 2;
    const int* src  = ei;
    const int* dstE = ei + E;
    const int* msrc = mei;
    const int* mdst = mei + M;

    float* bufA = (float*)d_ws;                 // N*64
    float* bufB = bufA + (size_t)N * 64;        // N*64 (agg / Q)
    float* bufC = bufB + (size_t)N * 64;        // N*64
    float* deg  = bufC + (size_t)N * 64;        // N
    float* outf = (float*)d_out;

    const int nbN   = (N + 63) / 64;
    const int nbE   = (int)(((long long)E * 16 + 255) / 256);
    const int nbM   = (int)(((long long)M * 16 + 255) / 256);

    // degrees -> inv_deg (in place in deg)
    hipMemsetAsync(deg, 0, (size_t)N * 4, stream);
    k_deg<<<(E + 255) / 256, 256, 0, stream>>>(dstE, deg, E);
    k_invdeg<<<(N + 255) / 256, 256, 0, stream>>>(deg, N);

    // h1 = relu(x @ lin1_w + b)          -> A
    node_mm<128, 0, true><<<nbN, 256, 0, stream>>>(
        x, nullptr, nullptr, lin1_w, nullptr, lin1_b, bufA, N);

    // sage1: agg = segsum(h1[src]) -> B; h2 = relu(agg*inv @ wl + bl + h1 @ wr) -> C
    hipMemsetAsync(bufB, 0, (size_t)N * 64 * 4, stream);
    k_scatter<<<nbE, 256, 0, stream>>>(bufA, src, dstE, bufB, E);
    node_mm<64, 64, true><<<nbN, 256, 0, stream>>>(
        bufB, deg, bufA, c1_wl, c1_wr, c1_bl, bufC, N);

    // h3 = relu(h2 @ lin2_w + b)         -> A
    node_mm<64, 0, true><<<nbN, 256, 0, stream>>>(
        bufC, nullptr, nullptr, lin2_w, nullptr, lin2_b, bufA, N);

    // sage2 -> C
    hipMemsetAsync(bufB, 0, (size_t)N * 64 * 4, stream);
    k_scatter<<<nbE, 256, 0, stream>>>(bufA, src, dstE, bufB, E);
    node_mm<64, 64, true><<<nbN, 256, 0, stream>>>(
        bufB, deg, bufA, c2_wl, c2_wr, c2_bl, bufC, N);

    // P = h4 @ W1[:64] + b1 -> A ; Q = h4 @ W1[64:] -> B
    node_mm<64, 0, false><<<nbN, 256, 0, stream>>>(
        bufC, nullptr, nullptr, mlp_w1, nullptr, mlp_b1, bufA, N);
    node_mm<64, 0, false><<<nbN, 256, 0, stream>>>(
        bufC, nullptr, nullptr, mlp_w1 + 64 * 64, nullptr, nullptr, bufB, N);

    // edge scoring
    k_score<<<nbM, 256, 0, stream>>>(bufA, bufB, msrc, mdst, mlp_w2, mlp_b2,
                                     outf, M);
}

// Round 2
// 1011.058 us; speedup vs baseline: 5.9004x; 5.9004x over previous
//
#include <hip/hip_runtime.h>
#include <math.h>

// ================= CSR build =================
__global__ __launch_bounds__(256) void k_hist(const int* __restrict__ dst,
                                              int* __restrict__ deg, int E) {
    int i = blockIdx.x * 256 + threadIdx.x;
    if (i < E) atomicAdd(&deg[dst[i]], 1);
}

__global__ __launch_bounds__(256) void k_blocksum(const int* __restrict__ deg,
                                                  int* __restrict__ partials, int n) {
    __shared__ int s[256];
    int i = blockIdx.x * 256 + threadIdx.x;
    s[threadIdx.x] = (i < n) ? deg[i] : 0;
    __syncthreads();
    for (int off = 128; off > 0; off >>= 1) {
        if (threadIdx.x < off) s[threadIdx.x] += s[threadIdx.x + off];
        __syncthreads();
    }
    if (threadIdx.x == 0) partials[blockIdx.x] = s[0];
}

// single block, 1024 threads: inclusive scan of partials (chunked for safety)
__global__ __launch_bounds__(1024) void k_scan_partials(int* partials, int nb) {
    __shared__ int s[1024];
    int carry = 0;
    for (int base = 0; base < nb; base += 1024) {
        int i = base + (int)threadIdx.x;
        int v = (i < nb) ? partials[i] : 0;
        s[threadIdx.x] = v;
        __syncthreads();
        for (int off = 1; off < 1024; off <<= 1) {
            int t = (threadIdx.x >= (unsigned)off) ? s[threadIdx.x - off] : 0;
            __syncthreads();
            s[threadIdx.x] += t;
            __syncthreads();
        }
        if (i < nb) partials[i] = s[threadIdx.x] + carry;
        int total = s[1023];
        __syncthreads();
        carry += total;
    }
}

// exclusive scan within block + global offset -> row_ptr, cursor, inv_deg
__global__ __launch_bounds__(256) void k_rowptr(const int* __restrict__ deg,
                                                const int* __restrict__ psum,
                                                int* __restrict__ row_ptr,
                                                int* __restrict__ cursor,
                                                float* __restrict__ inv_deg,
                                                int n, int E_) {
    __shared__ int s[256];
    int blk = blockIdx.x;
    int i = blk * 256 + (int)threadIdx.x;
    int d = (i < n) ? deg[i] : 0;
    s[threadIdx.x] = d;
    __syncthreads();
    for (int off = 1; off < 256; off <<= 1) {
        int t = (threadIdx.x >= (unsigned)off) ? s[threadIdx.x - off] : 0;
        __syncthreads();
        s[threadIdx.x] += t;
        __syncthreads();
    }
    int excl = s[threadIdx.x] - d;
    int offset = (blk == 0) ? 0 : psum[blk - 1];
    if (i < n) {
        int rp = offset + excl;
        row_ptr[i] = rp;
        cursor[i] = rp;
        inv_deg[i] = d > 0 ? 1.0f / (float)d : 0.0f;
    }
    if (i == 0) row_ptr[n] = E_;
}

__global__ __launch_bounds__(256) void k_fill(const int* __restrict__ src,
                                              const int* __restrict__ dst,
                                              int* __restrict__ cursor,
                                              int* __restrict__ csr, int E) {
    int e = blockIdx.x * 256 + threadIdx.x;
    if (e < E) {
        int pos = atomicAdd(&cursor[dst[e]], 1);
        csr[pos] = src[e];
    }
}

// ============== mean aggregation: gather via CSR ==============
// one 64-lane wave per node; lane = channel. Per neighbor: coalesced 256B row.
__global__ __launch_bounds__(256) void k_gather(const float* __restrict__ h,
                                                const int* __restrict__ csr,
                                                const int* __restrict__ row_ptr,
                                                const float* __restrict__ inv_deg,
                                                float* __restrict__ out, int n) {
    int wave = (blockIdx.x * 256 + (int)threadIdx.x) >> 6;
    if (wave >= n) return;
    int lane = threadIdx.x & 63;
    int start = row_ptr[wave], end = row_ptr[wave + 1];
    float acc = 0.0f;
    for (int base = start; base < end; base += 64) {
        int j = base + lane;
        int idx = (j < end) ? csr[j] : 0;
        int cnt = min(64, end - base);
        int k = 0;
        for (; k + 4 <= cnt; k += 4) {
            int s0 = __shfl(idx, k + 0, 64);
            int s1 = __shfl(idx, k + 1, 64);
            int s2 = __shfl(idx, k + 2, 64);
            int s3 = __shfl(idx, k + 3, 64);
            float v0 = h[(size_t)s0 * 64 + lane];
            float v1 = h[(size_t)s1 * 64 + lane];
            float v2 = h[(size_t)s2 * 64 + lane];
            float v3 = h[(size_t)s3 * 64 + lane];
            acc += v0; acc += v1; acc += v2; acc += v3;
        }
        for (; k < cnt; ++k) {
            int s = __shfl(idx, k, 64);
            acc += h[(size_t)s * 64 + lane];
        }
    }
    out[(size_t)wave * 64 + lane] = acc * inv_deg[wave];
}

// ---- fused node matmul: out[N,64] = act([A0(xscale)|A1] @ [W0;W1] + bias) ----
template <int K0, int K1, bool RELU>
__global__ __launch_bounds__(256) void node_mm(
    const float* __restrict__ A0, const float* __restrict__ scale0,
    const float* __restrict__ A1, const float* __restrict__ W0,
    const float* __restrict__ W1, const float* __restrict__ bias,
    float* __restrict__ out, int n) {
    constexpr int K = K0 + K1;
    constexpr int KV = K / 4;
    __shared__ float sA[64 * K];
    __shared__ float sW[K * 64];
    const int tid = threadIdx.x;
    const int row0 = blockIdx.x * 64;

    for (int i = tid; i < K0 * 16; i += 256)
        ((float4*)sW)[i] = ((const float4*)W0)[i];
    if (K1 > 0) {
        for (int i = tid; i < K1 * 16; i += 256)
            ((float4*)sW)[K0 * 16 + i] = ((const float4*)W1)[i];
    }

    for (int idx = tid; idx < 64 * KV; idx += 256) {
        int r = idx / KV, kc = idx % KV;
        int k = kc * 4;
        int grow = row0 + r;
        float4 v = make_float4(0.f, 0.f, 0.f, 0.f);
        if (grow < n) {
            if (k < K0) {
                v = *(const float4*)&A0[(size_t)grow * K0 + k];
                if (scale0) {
                    float sc = scale0[grow];
                    v.x *= sc; v.y *= sc; v.z *= sc; v.w *= sc;
                }
            } else {
                v = *(const float4*)&A1[(size_t)grow * K1 + (k - K0)];
            }
        }
        int kcs = kc ^ ((r >> 2) & 3);
        *(float4*)&sA[r * K + kcs * 4] = v;
    }
    __syncthreads();

    const int tc = tid & 15;
    const int tr = tid >> 4;
    const int sw = tr & 3;
    float4 acc[4];
#pragma unroll
    for (int rr = 0; rr < 4; ++rr) acc[rr] = make_float4(0.f, 0.f, 0.f, 0.f);

#pragma unroll 4
    for (int kc = 0; kc < KV; ++kc) {
        int ks = (kc ^ sw) * 4;
        float4 a[4], w[4];
#pragma unroll
        for (int rr = 0; rr < 4; ++rr)
            a[rr] = *(const float4*)&sA[(tr * 4 + rr) * K + ks];
#pragma unroll
        for (int kk = 0; kk < 4; ++kk)
            w[kk] = *(const float4*)&sW[(kc * 4 + kk) * 64 + tc * 4];
#pragma unroll
        for (int kk = 0; kk < 4; ++kk) {
#pragma unroll
            for (int rr = 0; rr < 4; ++rr) {
                float av = (&a[rr].x)[kk];
                acc[rr].x = fmaf(av, w[kk].x, acc[rr].x);
                acc[rr].y = fmaf(av, w[kk].y, acc[rr].y);
                acc[rr].z = fmaf(av, w[kk].z, acc[rr].z);
                acc[rr].w = fmaf(av, w[kk].w, acc[rr].w);
            }
        }
    }

    float4 b4 = make_float4(0.f, 0.f, 0.f, 0.f);
    if (bias) b4 = *(const float4*)&bias[tc * 4];
#pragma unroll
    for (int rr = 0; rr < 4; ++rr) {
        int r = row0 + tr * 4 + rr;
        if (r < n) {
            float4 v = acc[rr];
            v.x += b4.x; v.y += b4.y; v.z += b4.z; v.w += b4.w;
            if (RELU) {
                v.x = fmaxf(v.x, 0.f); v.y = fmaxf(v.y, 0.f);
                v.z = fmaxf(v.z, 0.f); v.w = fmaxf(v.w, 0.f);
            }
            *(float4*)&out[(size_t)r * 64 + tc * 4] = v;
        }
    }
}

// ---- edge scorer: out[e] = tanh( relu(P[s]+Q[d]) . w2 + b2 ) ----
__global__ __launch_bounds__(256) void k_score(
    const float* __restrict__ P, const float* __restrict__ Q,
    const int* __restrict__ msrc, const int* __restrict__ mdst,
    const float* __restrict__ w2, const float* __restrict__ b2,
    float* __restrict__ out, int M) {
    int gid = blockIdx.x * 256 + threadIdx.x;
    int e = gid >> 4;
    if (e >= M) return;
    int l = gid & 15;
    int s = msrc[e], d = mdst[e];
    float4 p = *(const float4*)&P[(size_t)s * 64 + l * 4];
    float4 q = *(const float4*)&Q[(size_t)d * 64 + l * 4];
    float4 w = *(const float4*)&w2[l * 4];
    float ux = fmaxf(p.x + q.x, 0.f);
    float uy = fmaxf(p.y + q.y, 0.f);
    float uz = fmaxf(p.z + q.z, 0.f);
    float uw = fmaxf(p.w + q.w, 0.f);
    float partial = ux * w.x + uy * w.y + uz * w.z + uw * w.w;
#pragma unroll
    for (int m = 1; m < 16; m <<= 1) partial += __shfl_xor(partial, m, 16);
    if (l == 0) out[e] = tanhf(partial + b2[0]);
}

extern "C" void kernel_launch(void* const* d_in, const int* in_sizes, int n_in,
                              void* d_out, int out_size, void* d_ws, size_t ws_size,
                              hipStream_t stream) {
    const float* x      = (const float*)d_in[0];
    const int*   ei     = (const int*)d_in[1];
    const int*   mei    = (const int*)d_in[2];
    const float* lin1_w = (const float*)d_in[3];
    const float* lin1_b = (const float*)d_in[4];
    const float* lin2_w = (const float*)d_in[5];
    const float* lin2_b = (const float*)d_in[6];
    const float* c1_wl  = (const float*)d_in[7];
    const float* c1_bl  = (const float*)d_in[8];
    const float* c1_wr  = (const float*)d_in[9];
    const float* c2_wl  = (const float*)d_in[10];
    const float* c2_bl  = (const float*)d_in[11];
    const float* c2_wr  = (const float*)d_in[12];
    const float* mlp_w1 = (const float*)d_in[13];
    const float* mlp_b1 = (const float*)d_in[14];
    const float* mlp_w2 = (const float*)d_in[15];
    const float* mlp_b2 = (const float*)d_in[16];

    const int N = in_sizes[0] / 128;
    const int E = in_sizes[1] / 2;
    const int M = in_sizes[2] / 2;
    const int* src  = ei;
    const int* dstE = ei + E;
    const int* msrc = mei;
    const int* mdst = mei + M;

    const size_t N64 = (size_t)N * 64;
    float* bufA    = (float*)d_ws;              // N*64
    float* bufB    = bufA + N64;                // N*64
    float* bufC    = bufB + N64;                // N*64
    float* inv_deg = bufC + N64;                // N
    int*   deg_i   = (int*)(inv_deg + N);       // N
    int*   row_ptr = deg_i + N;                 // N+1
    int*   cursor  = row_ptr + (N + 1);         // N
    int*   partials= cursor + N;                // nb
    const int nb   = (N + 255) / 256;
    int*   csr     = partials + ((nb + 63) & ~63); // E
    float* outf = (float*)d_out;

    const int nbN = (N + 63) / 64;
    const int nbE = (E + 255) / 256;
    const int nbM = (int)(((long long)M * 16 + 255) / 256);
    const int nbG = (int)(((long long)N * 64 + 255) / 256);

    // ---- CSR build (once; both SAGE layers share edge_index) ----
    hipMemsetAsync(deg_i, 0, (size_t)N * 4, stream);
    k_hist<<<nbE, 256, 0, stream>>>(dstE, deg_i, E);
    k_blocksum<<<nb, 256, 0, stream>>>(deg_i, partials, N);
    k_scan_partials<<<1, 1024, 0, stream>>>(partials, nb);
    k_rowptr<<<nb, 256, 0, stream>>>(deg_i, partials, row_ptr, cursor, inv_deg, N, E);
    k_fill<<<nbE, 256, 0, stream>>>(src, dstE, cursor, csr, E);

    // h1 = relu(x @ lin1_w + b)          -> A
    node_mm<128, 0, true><<<nbN, 256, 0, stream>>>(
        x, nullptr, nullptr, lin1_w, nullptr, lin1_b, bufA, N);

    // sage1: agg = mean gather -> B; h2 = relu(agg @ wl + bl + h1 @ wr) -> C
    k_gather<<<nbG, 256, 0, stream>>>(bufA, csr, row_ptr, inv_deg, bufB, N);
    node_mm<64, 64, true><<<nbN, 256, 0, stream>>>(
        bufB, nullptr, bufA, c1_wl, c1_wr, c1_bl, bufC, N);

    // h3 = relu(h2 @ lin2_w + b)         -> A
    node_mm<64, 0, true><<<nbN, 256, 0, stream>>>(
        bufC, nullptr, nullptr, lin2_w, nullptr, lin2_b, bufA, N);

    // sage2 -> C
    k_gather<<<nbG, 256, 0, stream>>>(bufA, csr, row_ptr, inv_deg, bufB, N);
    node_mm<64, 64, true><<<nbN, 256, 0, stream>>>(
        bufB, nullptr, bufA, c2_wl, c2_wr, c2_bl, bufC, N);

    // P = h4 @ W1[:64] + b1 -> A ; Q = h4 @ W1[64:] -> B
    node_mm<64, 0, false><<<nbN, 256, 0, stream>>>(
        bufC, nullptr, nullptr, mlp_w1, nullptr, mlp_b1, bufA, N);
    node_mm<64, 0, false><<<nbN, 256, 0, stream>>>(
        bufC, nullptr, nullptr, mlp_w1 + 64 * 64, nullptr, nullptr, bufB, N);

    // edge scoring
    k_score<<<nbM, 256, 0, stream>>>(bufA, bufB, msrc, mdst, mlp_w2, mlp_b2,
                                     outf, M);
}